// Round 10
// baseline (119.888 us; speedup 1.0000x reference)
//
#include <hip/hip_runtime.h>
#include <math.h>

#define KMAX   32
#define CIN    64
#define COUT   64
#define NKERN  27
#define GPW    8          // points per wave, gather kernel
#define MMT    2          // 16-row tiles per wave, matmul kernels
constexpr float BN_EPS = 1e-5f;

typedef _Float16 f16;
typedef _Float16 f16x2 __attribute__((ext_vector_type(2)));
typedef _Float16 f16x8 __attribute__((ext_vector_type(8)));
typedef float    f32x4 __attribute__((ext_vector_type(4)));

// ---------------- kernel A: cvt f32->f16 + zero stats + zeros-row -----
__global__ __launch_bounds__(256) void k_cvt(const float* __restrict__ in,
                                             f16* __restrict__ out,
                                             float* __restrict__ stats,
                                             f16* __restrict__ zrow,
                                             int total4) {
    if (blockIdx.x == 0) {
        if (threadIdx.x < 128) stats[threadIdx.x] = 0.0f;
        if (threadIdx.x < CIN) zrow[threadIdx.x] = (f16)0.0f;
    }
    const int stride = gridDim.x * blockDim.x;
    for (int i = blockIdx.x * blockDim.x + threadIdx.x; i < total4; i += stride) {
        const float4 v = ((const float4*)in)[i];
        f16x2 a = { (f16)v.x, (f16)v.y };
        f16x2 b = { (f16)v.z, (f16)v.w };
        uint2 u;
        u.x = *(const unsigned int*)&a;
        u.y = *(const unsigned int*)&b;
        ((uint2*)out)[i] = u;
    }
}

// ---------------- kernel B: pack dw into MFMA B-fragment layout -------
// Fragment entry i = (j*2+s)*64 + l (col-tile j, k-step s, lane l):
// dwf[i*8+e] = dw[s*32 + (l>>4)*8 + e][j*16 + (l&15)]
__global__ void k_prep_dw(const float* __restrict__ dw, f16* __restrict__ dwf) {
    for (int i = threadIdx.x; i < 512; i += 256) {
        const int j = i >> 7, s = (i >> 6) & 1, l = i & 63;
        const int col = j * 16 + (l & 15);
        const int k0  = s * 32 + ((l >> 4) * 8);
        #pragma unroll
        for (int e = 0; e < 8; ++e)
            dwf[(size_t)i * 8 + e] = (f16)dw[(k0 + e) * COUT + col];
    }
}

// ---------------- kernel G: PURE gather + spatial filter --------------
// n forced wave-uniform via readfirstlane -> idx/flt/cnt become s_loads,
// validity select is s_cselect, gather = SGPR base + one shared voffset.
__global__ __launch_bounds__(256, 8) void k_gather(
    const f16*   __restrict__ gh,          // f16[(N+1),64], row N = zeros
    const float* __restrict__ sw,          // [27,64]
    const int*   __restrict__ nn_count,    // [N]
    const int*   __restrict__ nn_index,    // [N,32]
    const int*   __restrict__ filt_index,  // [N,32]
    f16*         __restrict__ sp,          // [N,64] out
    int zrowIdx)                           // = N
{
    __shared__ float sw_lds[NKERN * CIN];  // 6.75 KB
    const int tid = threadIdx.x;
    for (int i = tid; i < NKERN * CIN; i += 256) sw_lds[i] = sw[i];
    __syncthreads();

    const int wave = tid >> 6;
    const int lane = tid & 63;
    const int base = blockIdx.x * (4 * GPW) + wave * GPW;

    for (int p = 0; p < GPW; ++p) {
        const int n = __builtin_amdgcn_readfirstlane(base + p);  // uniform
        const int cnt = nn_count[n];                             // s_load
        const int* __restrict__ ni = nn_index   + (size_t)n * KMAX;
        const int* __restrict__ fi = filt_index + (size_t)n * KMAX;

        int idx[32], flt[32];
        #pragma unroll
        for (int k = 0; k < 32; ++k) {
            idx[k] = (k < cnt) ? ni[k] : zrowIdx;   // scalar select
            flt[k] = fi[k];                         // s_load
        }

        f16 g[32];
        #pragma unroll
        for (int k = 0; k < 32; ++k)                // 32 loads, SGPR bases
            g[k] = gh[(size_t)idx[k] * CIN + lane];

        float a0 = 0.f, a1 = 0.f, a2 = 0.f, a3 = 0.f;
        #pragma unroll
        for (int k = 0; k < 32; ++k) {
            float& a = (k & 3) == 0 ? a0 : (k & 3) == 1 ? a1
                     : (k & 3) == 2 ? a2 : a3;
            a = fmaf((float)g[k], sw_lds[flt[k] * CIN + lane], a);
        }
        sp[(size_t)n * CIN + lane] = (f16)(((a0 + a1) + (a2 + a3)) / (float)cnt);
    }
}

// ---------------- MFMA matmul body shared by both passes --------------
// Per wave, per 16-row tile: x[m][c] = relu(sp[16x64] @ dw[64x64] + bias).
// A-frag: lane holds sp[r0 + (l&15)][(l>>4)*8 + e (+32)]  (contiguous f16x8)
// C-frag: row = (l>>4)*4 + r, col = j*16 + (l&15)          (m89-verified)
#define MM_LOAD_AB(r0)                                                        \
    const f16* arow = sp + (size_t)((r0) + (lane & 15)) * CIN + ((lane >> 4) * 8); \
    const f16x8 a0 = *(const f16x8*)(arow);                                   \
    const f16x8 a1 = *(const f16x8*)(arow + 32);

// ---------------- kernel M1: MFMA matmul + relu -> BN stats -----------
__global__ __launch_bounds__(256) void k_mm_stats(
    const f16*   __restrict__ sp,          // [N,64]
    const f16*   __restrict__ dwf,         // packed B-frags
    const float* __restrict__ bias,        // [1,64]
    float*       __restrict__ stats)       // [128]
{
    __shared__ float rsum[4][4][16], rsq[4][4][16];
    const int tid = threadIdx.x;
    const int wave = tid >> 6, lane = tid & 63;

    const f16x8* dwf8 = (const f16x8*)dwf;
    f16x8 b[4][2];
    #pragma unroll
    for (int j = 0; j < 4; ++j) {
        b[j][0] = dwf8[(j * 2 + 0) * 64 + lane];
        b[j][1] = dwf8[(j * 2 + 1) * 64 + lane];
    }
    float bias_c[4];
    #pragma unroll
    for (int j = 0; j < 4; ++j) bias_c[j] = bias[j * 16 + (lane & 15)];

    float sum[4] = {0, 0, 0, 0}, sq[4] = {0, 0, 0, 0};
    const int rowbase = (blockIdx.x * 4 + wave) * (MMT * 16);

    for (int t = 0; t < MMT; ++t) {
        MM_LOAD_AB(rowbase + t * 16)
        #pragma unroll
        for (int j = 0; j < 4; ++j) {
            f32x4 acc = {0.f, 0.f, 0.f, 0.f};
            acc = __builtin_amdgcn_mfma_f32_16x16x32_f16(a0, b[j][0], acc, 0, 0, 0);
            acc = __builtin_amdgcn_mfma_f32_16x16x32_f16(a1, b[j][1], acc, 0, 0, 0);
            #pragma unroll
            for (int r = 0; r < 4; ++r) {
                const float x = fmaxf(acc[r] + bias_c[j], 0.0f);
                sum[j] += x;
                sq[j]  += x * x;
            }
        }
    }

    #pragma unroll
    for (int j = 0; j < 4; ++j) {
        sum[j] += __shfl_xor(sum[j], 16); sum[j] += __shfl_xor(sum[j], 32);
        sq[j]  += __shfl_xor(sq[j], 16);  sq[j]  += __shfl_xor(sq[j], 32);
    }
    if (lane < 16) {
        #pragma unroll
        for (int j = 0; j < 4; ++j) {
            rsum[wave][j][lane] = sum[j];
            rsq[wave][j][lane]  = sq[j];
        }
    }
    __syncthreads();
    if (wave == 0 && lane < 16) {
        #pragma unroll
        for (int j = 0; j < 4; ++j) {
            const float s = rsum[0][j][lane] + rsum[1][j][lane]
                          + rsum[2][j][lane] + rsum[3][j][lane];
            const float q = rsq[0][j][lane] + rsq[1][j][lane]
                          + rsq[2][j][lane] + rsq[3][j][lane];
            atomicAdd(&stats[j * 16 + lane], s);
            atomicAdd(&stats[COUT + j * 16 + lane], q);
        }
    }
}

// ---------------- kernel 2: finalize BN scale/shift -------------------
__global__ void k_finalize(const float* __restrict__ stats,
                           const float* __restrict__ gamma,
                           const float* __restrict__ beta,
                           float* __restrict__ sc_sh, float invN) {
    const int j = threadIdx.x;               // 64 threads
    const float mean = stats[j] * invN;
    const float var  = stats[COUT + j] * invN - mean * mean;
    const float s    = gamma[j] * rsqrtf(var + BN_EPS);
    sc_sh[j]        = s;
    sc_sh[COUT + j] = beta[j] - mean * s;
}

// ---------------- kernel M2: MFMA matmul + relu + BN -> d_out ---------
__global__ __launch_bounds__(256) void k_mm_out(
    const f16*   __restrict__ sp,          // [N,64]
    const f16*   __restrict__ dwf,         // packed B-frags
    const float* __restrict__ bias,        // [1,64]
    const float* __restrict__ sc_sh,       // [128]
    float*       __restrict__ out)         // [N,64]
{
    const int tid = threadIdx.x;
    const int wave = tid >> 6, lane = tid & 63;

    const f16x8* dwf8 = (const f16x8*)dwf;
    f16x8 b[4][2];
    #pragma unroll
    for (int j = 0; j < 4; ++j) {
        b[j][0] = dwf8[(j * 2 + 0) * 64 + lane];
        b[j][1] = dwf8[(j * 2 + 1) * 64 + lane];
    }
    float bias_c[4], sc[4], sh[4];
    #pragma unroll
    for (int j = 0; j < 4; ++j) {
        const int c = j * 16 + (lane & 15);
        bias_c[j] = bias[c];
        sc[j]     = sc_sh[c];
        sh[j]     = sc_sh[COUT + c];
    }

    const int rowbase = (blockIdx.x * 4 + wave) * (MMT * 16);
    for (int t = 0; t < MMT; ++t) {
        const int r0 = rowbase + t * 16;
        MM_LOAD_AB(r0)
        #pragma unroll
        for (int j = 0; j < 4; ++j) {
            f32x4 acc = {0.f, 0.f, 0.f, 0.f};
            acc = __builtin_amdgcn_mfma_f32_16x16x32_f16(a0, b[j][0], acc, 0, 0, 0);
            acc = __builtin_amdgcn_mfma_f32_16x16x32_f16(a1, b[j][1], acc, 0, 0, 0);
            #pragma unroll
            for (int r = 0; r < 4; ++r) {
                const float x = fmaxf(acc[r] + bias_c[j], 0.0f);
                out[(size_t)(r0 + (lane >> 4) * 4 + r) * COUT + j * 16 + (lane & 15)]
                    = fmaf(x, sc[j], sh[j]);
            }
        }
    }
}

extern "C" void kernel_launch(void* const* d_in, const int* in_sizes, int n_in,
                              void* d_out, int out_size, void* d_ws, size_t ws_size,
                              hipStream_t stream) {
    const float* inputs     = (const float*)d_in[0];
    const float* sw         = (const float*)d_in[1];
    const float* dw         = (const float*)d_in[2];
    const float* bias       = (const float*)d_in[3];
    const float* gamma      = (const float*)d_in[4];
    const float* beta       = (const float*)d_in[5];
    const int*   nn_count   = (const int*)d_in[6];
    const int*   nn_index   = (const int*)d_in[7];
    const int*   filt_index = (const int*)d_in[8];

    const int N = in_sizes[0] / CIN;           // 65536
    float* out   = (float*)d_out;

    // ws: stats(128f) | sc_sh(128f) | in_h((N+1)*64 f16) | sp(N*64 f16) | dwf(4096 f16)
    float* stats = (float*)d_ws;
    float* sc_sh = (float*)d_ws + 128;
    f16*   in_h  = (f16*)((float*)d_ws + 256);
    f16*   spb   = in_h + (size_t)(N + 1) * CIN;
    f16*   dwf   = spb + (size_t)N * CIN;

    k_cvt<<<2048, 256, 0, stream>>>(inputs, in_h, stats,
                                    in_h + (size_t)N * CIN, N * CIN / 4);
    k_prep_dw<<<1, 256, 0, stream>>>(dw, dwf);

    k_gather<<<N / (4 * GPW), 256, 0, stream>>>(
        in_h, sw, nn_count, nn_index, filt_index, spb, N);

    k_mm_stats<<<N / (4 * MMT * 16), 256, 0, stream>>>(spb, dwf, bias, stats);
    k_finalize<<<1, COUT, 0, stream>>>(stats, gamma, beta, sc_sh, 1.0f / (float)N);
    k_mm_out<<<N / (4 * MMT * 16), 256, 0, stream>>>(spb, dwf, bias, sc_sh, out);
}

// Round 11
// 92.393 us; speedup vs baseline: 1.2976x; 1.2976x over previous
//
#include <hip/hip_runtime.h>
#include <math.h>

#define KMAX   32
#define CIN    64
#define COUT   64
#define NKERN  27
#define GPW    8          // points per wave, gather kernel
#define MMT    2          // 16-row tiles per wave, matmul kernels
constexpr float BN_EPS = 1e-5f;

typedef _Float16 f16;
typedef _Float16 f16x2 __attribute__((ext_vector_type(2)));
typedef _Float16 f16x8 __attribute__((ext_vector_type(8)));
typedef float    f32x4 __attribute__((ext_vector_type(4)));

// ---------------- kernel A: cvt f32->f16 + zero stats + zeros-row -----
__global__ __launch_bounds__(256) void k_cvt(const float* __restrict__ in,
                                             f16* __restrict__ out,
                                             float* __restrict__ stats,
                                             f16* __restrict__ zrow,
                                             int total4) {
    if (blockIdx.x == 0) {
        if (threadIdx.x < 128) stats[threadIdx.x] = 0.0f;
        if (threadIdx.x < CIN) zrow[threadIdx.x] = (f16)0.0f;
    }
    const int stride = gridDim.x * blockDim.x;
    for (int i = blockIdx.x * blockDim.x + threadIdx.x; i < total4; i += stride) {
        const float4 v = ((const float4*)in)[i];
        f16x2 a = { (f16)v.x, (f16)v.y };
        f16x2 b = { (f16)v.z, (f16)v.w };
        uint2 u;
        u.x = *(const unsigned int*)&a;
        u.y = *(const unsigned int*)&b;
        ((uint2*)out)[i] = u;
    }
}

// ---------------- kernel B: pack dw into MFMA B-fragment layout -------
// Fragment entry i = (j*2+s)*64 + l (col-tile j, k-step s, lane l):
// dwf[i*8+e] = dw[s*32 + (l>>4)*8 + e][j*16 + (l&15)]
__global__ void k_prep_dw(const float* __restrict__ dw, f16* __restrict__ dwf) {
    for (int i = threadIdx.x; i < 512; i += 256) {
        const int j = i >> 7, s = (i >> 6) & 1, l = i & 63;
        const int col = j * 16 + (l & 15);
        const int k0  = s * 32 + ((l >> 4) * 8);
        #pragma unroll
        for (int e = 0; e < 8; ++e)
            dwf[(size_t)i * 8 + e] = (f16)dw[(k0 + e) * COUT + col];
    }
}

// ---------------- kernel G: PURE gather + spatial filter (R9 exact) ---
// Vector-path indices (int4), zeros-row select, 32 unconditional gathers.
__global__ __launch_bounds__(256, 4) void k_gather(
    const f16*   __restrict__ gh,          // f16[(N+1),64], row N = zeros
    const float* __restrict__ sw,          // [27,64]
    const int*   __restrict__ nn_count,    // [N]
    const int*   __restrict__ nn_index,    // [N,32]
    const int*   __restrict__ filt_index,  // [N,32]
    f16*         __restrict__ sp,          // [N,64] out
    int zrowIdx)                           // = N
{
    __shared__ float sw_lds[NKERN * CIN];  // 6.75 KB
    const int tid = threadIdx.x;
    for (int i = tid; i < NKERN * CIN; i += 256) sw_lds[i] = sw[i];
    __syncthreads();

    const int wave = tid >> 6;
    const int lane = tid & 63;
    const int base = blockIdx.x * (4 * GPW) + wave * GPW;

    for (int p = 0; p < GPW; ++p) {
        const int n   = base + p;
        const int cnt = nn_count[n];
        const int4* __restrict__ ni4 = (const int4*)(nn_index   + (size_t)n * KMAX);
        const int4* __restrict__ fi4 = (const int4*)(filt_index + (size_t)n * KMAX);

        int idx[32], flt[32];
        #pragma unroll
        for (int q = 0; q < 8; ++q) {
            *(int4*)&idx[4 * q] = ni4[q];
            *(int4*)&flt[4 * q] = fi4[q];
        }
        // invalid neighbors -> zeros row (same L1-resident line for all)
        #pragma unroll
        for (int k = 0; k < 32; ++k) idx[k] = (k < cnt) ? idx[k] : zrowIdx;

        f16 g[32];
        #pragma unroll
        for (int k = 0; k < 32; ++k)           // 32 independent gathers
            g[k] = gh[(size_t)idx[k] * CIN + lane];

        float a0 = 0.f, a1 = 0.f, a2 = 0.f, a3 = 0.f;
        #pragma unroll
        for (int k = 0; k < 32; ++k) {
            float& a = (k & 3) == 0 ? a0 : (k & 3) == 1 ? a1
                     : (k & 3) == 2 ? a2 : a3;
            a = fmaf((float)g[k], sw_lds[flt[k] * CIN + lane], a);
        }
        sp[(size_t)n * CIN + lane] = (f16)(((a0 + a1) + (a2 + a3)) / (float)cnt);
    }
}

// ---------------- MFMA matmul body shared by both passes --------------
// A-frag: lane holds sp[r0 + (l&15)][(l>>4)*8 + e (+32)]  (contiguous f16x8)
// C-frag: row = (l>>4)*4 + r, col = j*16 + (l&15)          (m89-verified)
#define MM_LOAD_AB(r0)                                                        \
    const f16* arow = sp + (size_t)((r0) + (lane & 15)) * CIN + ((lane >> 4) * 8); \
    const f16x8 a0 = *(const f16x8*)(arow);                                   \
    const f16x8 a1 = *(const f16x8*)(arow + 32);

// ---------------- kernel M1: MFMA matmul + relu -> BN stats -----------
__global__ __launch_bounds__(256) void k_mm_stats(
    const f16*   __restrict__ sp,          // [N,64]
    const f16*   __restrict__ dwf,         // packed B-frags
    const float* __restrict__ bias,        // [1,64]
    float*       __restrict__ stats)       // [128]
{
    __shared__ float rsum[4][4][16], rsq[4][4][16];
    const int tid = threadIdx.x;
    const int wave = tid >> 6, lane = tid & 63;

    const f16x8* dwf8 = (const f16x8*)dwf;
    f16x8 b[4][2];
    #pragma unroll
    for (int j = 0; j < 4; ++j) {
        b[j][0] = dwf8[(j * 2 + 0) * 64 + lane];
        b[j][1] = dwf8[(j * 2 + 1) * 64 + lane];
    }
    float bias_c[4];
    #pragma unroll
    for (int j = 0; j < 4; ++j) bias_c[j] = bias[j * 16 + (lane & 15)];

    float sum[4] = {0, 0, 0, 0}, sq[4] = {0, 0, 0, 0};
    const int rowbase = (blockIdx.x * 4 + wave) * (MMT * 16);

    for (int t = 0; t < MMT; ++t) {
        MM_LOAD_AB(rowbase + t * 16)
        #pragma unroll
        for (int j = 0; j < 4; ++j) {
            f32x4 acc = {0.f, 0.f, 0.f, 0.f};
            acc = __builtin_amdgcn_mfma_f32_16x16x32_f16(a0, b[j][0], acc, 0, 0, 0);
            acc = __builtin_amdgcn_mfma_f32_16x16x32_f16(a1, b[j][1], acc, 0, 0, 0);
            #pragma unroll
            for (int r = 0; r < 4; ++r) {
                const float x = fmaxf(acc[r] + bias_c[j], 0.0f);
                sum[j] += x;
                sq[j]  += x * x;
            }
        }
    }

    #pragma unroll
    for (int j = 0; j < 4; ++j) {
        sum[j] += __shfl_xor(sum[j], 16); sum[j] += __shfl_xor(sum[j], 32);
        sq[j]  += __shfl_xor(sq[j], 16);  sq[j]  += __shfl_xor(sq[j], 32);
    }
    if (lane < 16) {
        #pragma unroll
        for (int j = 0; j < 4; ++j) {
            rsum[wave][j][lane] = sum[j];
            rsq[wave][j][lane]  = sq[j];
        }
    }
    __syncthreads();
    if (wave == 0 && lane < 16) {
        #pragma unroll
        for (int j = 0; j < 4; ++j) {
            const float s = rsum[0][j][lane] + rsum[1][j][lane]
                          + rsum[2][j][lane] + rsum[3][j][lane];
            const float q = rsq[0][j][lane] + rsq[1][j][lane]
                          + rsq[2][j][lane] + rsq[3][j][lane];
            atomicAdd(&stats[j * 16 + lane], s);
            atomicAdd(&stats[COUT + j * 16 + lane], q);
        }
    }
}

// ---------------- kernel 2: finalize BN scale/shift -------------------
__global__ void k_finalize(const float* __restrict__ stats,
                           const float* __restrict__ gamma,
                           const float* __restrict__ beta,
                           float* __restrict__ sc_sh, float invN) {
    const int j = threadIdx.x;               // 64 threads
    const float mean = stats[j] * invN;
    const float var  = stats[COUT + j] * invN - mean * mean;
    const float s    = gamma[j] * rsqrtf(var + BN_EPS);
    sc_sh[j]        = s;
    sc_sh[COUT + j] = beta[j] - mean * s;
}

// ---------------- kernel M2: MFMA matmul + relu + BN -> d_out ---------
__global__ __launch_bounds__(256) void k_mm_out(
    const f16*   __restrict__ sp,          // [N,64]
    const f16*   __restrict__ dwf,         // packed B-frags
    const float* __restrict__ bias,        // [1,64]
    const float* __restrict__ sc_sh,       // [128]
    float*       __restrict__ out)         // [N,64]
{
    const int tid = threadIdx.x;
    const int wave = tid >> 6, lane = tid & 63;

    const f16x8* dwf8 = (const f16x8*)dwf;
    f16x8 b[4][2];
    #pragma unroll
    for (int j = 0; j < 4; ++j) {
        b[j][0] = dwf8[(j * 2 + 0) * 64 + lane];
        b[j][1] = dwf8[(j * 2 + 1) * 64 + lane];
    }
    float bias_c[4], sc[4], sh[4];
    #pragma unroll
    for (int j = 0; j < 4; ++j) {
        const int c = j * 16 + (lane & 15);
        bias_c[j] = bias[c];
        sc[j]     = sc_sh[c];
        sh[j]     = sc_sh[COUT + c];
    }

    const int rowbase = (blockIdx.x * 4 + wave) * (MMT * 16);
    for (int t = 0; t < MMT; ++t) {
        const int r0 = rowbase + t * 16;
        MM_LOAD_AB(r0)
        #pragma unroll
        for (int j = 0; j < 4; ++j) {
            f32x4 acc = {0.f, 0.f, 0.f, 0.f};
            acc = __builtin_amdgcn_mfma_f32_16x16x32_f16(a0, b[j][0], acc, 0, 0, 0);
            acc = __builtin_amdgcn_mfma_f32_16x16x32_f16(a1, b[j][1], acc, 0, 0, 0);
            #pragma unroll
            for (int r = 0; r < 4; ++r) {
                const float x = fmaxf(acc[r] + bias_c[j], 0.0f);
                out[(size_t)(r0 + (lane >> 4) * 4 + r) * COUT + j * 16 + (lane & 15)]
                    = fmaf(x, sc[j], sh[j]);
            }
        }
    }
}

extern "C" void kernel_launch(void* const* d_in, const int* in_sizes, int n_in,
                              void* d_out, int out_size, void* d_ws, size_t ws_size,
                              hipStream_t stream) {
    const float* inputs     = (const float*)d_in[0];
    const float* sw         = (const float*)d_in[1];
    const float* dw         = (const float*)d_in[2];
    const float* bias       = (const float*)d_in[3];
    const float* gamma      = (const float*)d_in[4];
    const float* beta       = (const float*)d_in[5];
    const int*   nn_count   = (const int*)d_in[6];
    const int*   nn_index   = (const int*)d_in[7];
    const int*   filt_index = (const int*)d_in[8];

    const int N = in_sizes[0] / CIN;           // 65536
    float* out   = (float*)d_out;

    // ws: stats(128f) | sc_sh(128f) | in_h((N+1)*64 f16) | sp(N*64 f16) | dwf(4096 f16)
    float* stats = (float*)d_ws;
    float* sc_sh = (float*)d_ws + 128;
    f16*   in_h  = (f16*)((float*)d_ws + 256);
    f16*   spb   = in_h + (size_t)(N + 1) * CIN;
    f16*   dwf   = spb + (size_t)N * CIN;

    k_cvt<<<2048, 256, 0, stream>>>(inputs, in_h, stats,
                                    in_h + (size_t)N * CIN, N * CIN / 4);
    k_prep_dw<<<1, 256, 0, stream>>>(dw, dwf);

    k_gather<<<N / (4 * GPW), 256, 0, stream>>>(
        in_h, sw, nn_count, nn_index, filt_index, spb, N);

    k_mm_stats<<<N / (4 * MMT * 16), 256, 0, stream>>>(spb, dwf, bias, stats);
    k_finalize<<<1, COUT, 0, stream>>>(stats, gamma, beta, sc_sh, 1.0f / (float)N);
    k_mm_out<<<N / (4 * MMT * 16), 256, 0, stream>>>(spb, dwf, bias, sc_sh, out);
}